// Round 3
// baseline (463.523 us; speedup 1.0000x reference)
//
#include <hip/hip_runtime.h>
#include <hip/hip_bf16.h>
#include <float.h>

// Problem constants (PQHotShared): U[16384,64], B[64,4096], codebook[2048,16]
static constexpr int KCB    = 2048;   // codebook entries
static constexpr int DSUB   = 16;    // subvector length
static constexpr int NSUB_U = 65536; // 16384*64/16
static constexpr int NSUB_B = 16384; // 64*4096/16
static constexpr int NSUB   = NSUB_U + NSUB_B; // 81920
static constexpr int NQ     = 4;     // codebook split for load balance
static constexpr int CPQ    = KCB / NQ; // 512

typedef __attribute__((ext_vector_type(8))) short s16x8;   // 8 x bf16 (4 VGPRs)
typedef __attribute__((ext_vector_type(4))) float f32x4;
typedef __attribute__((ext_vector_type(2))) float f32x2;   // VGPR/SGPR pair

// ---------------- ws layout (bytes) ----------------
// CBPK (packed codebook pairs, 128 KB) overlays the UQH region: it is dead
// before pq_combine writes Uqh (stream-ordered), so ws stays ~5.25 MB.
static constexpr size_t OFF_PBEST = 0;
static constexpr size_t OFF_PIDX  = 1310720;
static constexpr size_t OFF_CBPK  = 2629632;   // overlaps UQH
static constexpr size_t OFF_UQH   = 2629632;
static constexpr size_t OFF_BQTH  = 4726784;

// Interleave codebook pairs: cbpk[p][k] = {cb[2p][k], cb[2p+1][k]}.
// Pure f32 copies -> zero numerics impact. Enables s_load_dwordx* of packed
// pairs feeding v_pk_fma_f32 (one SGPR-pair operand per packed FMA).
__global__ __launch_bounds__(256) void pq_prepack(const float* __restrict__ cb,
                                                  f32x2* __restrict__ cbpk) {
    int idx = blockIdx.x * 256 + threadIdx.x;   // 0..16383
    int p = idx >> 4;          // pair index 0..1023
    int k = idx & 15;
    f32x2 v;
    v[0] = cb[(size_t)p * 32 + k];
    v[1] = cb[(size_t)p * 32 + 16 + k];
    cbpk[idx] = v;
}

// One WAVE per (64-subvector chunk, codebook quarter); quarter is
// BLOCK-uniform (q = blockIdx.x & 3) and the quarter's ||c||^2 values are
// computed once per block into LDS with the EXACT op order of the original
// cb2_kernel (fmaf(v,v,0); r[j]=a[j]+a[j+8]; pairwise tree).
// Distance chains now use v_pk_fma_f32: each packed FMA advances TWO
// codewords' chains; per component it is an IEEE fp32 fma with the same
// ascending k order as the reference chain -> bit-identical distances.
// Selection: value-only fmin tree per 8 codewords + strict-'<' running
// (best, block-base); the winning 8-block is re-scanned once after the loop
// with the identical chain (bit-identical recompute) to recover the index.
// Strict '<' at both levels == first-index-wins sequential scan.
__global__ __launch_bounds__(256) void pq_partial(
    const float* __restrict__ U, const float* __restrict__ B,
    const float* __restrict__ rsU, const float* __restrict__ rsB,
    const float* __restrict__ cb, const f32x2* __restrict__ cbpk,
    float* __restrict__ pbest, int* __restrict__ pidx)
{
    __shared__ float c2S[CPQ];
    const int q     = blockIdx.x & 3;     // codebook quarter, block-uniform
    const int chunk = blockIdx.x >> 2;    // 256-subvector chunk, 0..319
    const int c0    = q * CPQ;

    // ---- stage ||c||^2 for this quarter into LDS (2 entries per thread) ----
    {
        const int e = threadIdx.x * 2;
        const float* p = cb + (size_t)(c0 + e) * DSUB;
#pragma unroll
        for (int t = 0; t < 2; t++) {
            float a[16];
#pragma unroll
            for (int j = 0; j < 16; j++) { float v = p[t * 16 + j]; a[j] = fmaf(v, v, 0.0f); }
            float r[8];
#pragma unroll
            for (int j = 0; j < 8; j++) r[j] = a[j] + a[j + 8];
            c2S[e + t] = ((r[0] + r[1]) + (r[2] + r[3])) + ((r[4] + r[5]) + (r[6] + r[7]));
        }
    }
    __syncthreads();

    const int wave = __builtin_amdgcn_readfirstlane(threadIdx.x >> 6); // SGPR
    const int lane = threadIdx.x & 63;
    const int sub  = chunk * 256 + wave * 64 + lane;   // per-lane subvector

    const float* wp;
    float rs;
    if (sub < NSUB_U) {                // whole block on one side: uniform branch
        wp = U + (size_t)sub * DSUB;
        rs = rsU[sub >> 2];
    } else {
        int s = sub - NSUB_U;
        wp = B + (size_t)s * DSUB;
        rs = rsB[s >> 8];
    }
    // g duplicated into both halves of a VGPR pair: v_pk_fma broadcasts
    // without op_sel modifiers (one-time cost, reused by all 2048 pk-fmas).
    f32x2 gg[16];
#pragma unroll
    for (int k = 0; k < 16; k++) {
        float gv = wp[k] / rs;          // IEEE div, matches np
        gg[k][0] = gv; gg[k][1] = gv;
    }

    const f32x2* cbq = cbpk + (size_t)q * (CPQ / 2) * DSUB;  // uniform base

    float best = FLT_MAX;
    int cbase = 0;
#pragma unroll 1
    for (int c = 0; c < CPQ; c += 8) {   // 4 packed chains = 8 codewords
        const f32x2* pp = cbq + (size_t)(c >> 1) * DSUB;     // uniform addr
        f32x2 d01 = {0.f, 0.f}, d23 = {0.f, 0.f};
        f32x2 d45 = {0.f, 0.f}, d67 = {0.f, 0.f};
#pragma unroll
        for (int k = 0; k < 16; k++) {
            asm("v_pk_fma_f32 %0, %1, %2, %0" : "+v"(d01) : "v"(gg[k]), "s"(pp[k]));
            asm("v_pk_fma_f32 %0, %1, %2, %0" : "+v"(d23) : "v"(gg[k]), "s"(pp[DSUB + k]));
            asm("v_pk_fma_f32 %0, %1, %2, %0" : "+v"(d45) : "v"(gg[k]), "s"(pp[2 * DSUB + k]));
            asm("v_pk_fma_f32 %0, %1, %2, %0" : "+v"(d67) : "v"(gg[k]), "s"(pp[3 * DSUB + k]));
        }
        float e0 = fmaf(-2.0f, d01[0], c2S[c + 0]);
        float e1 = fmaf(-2.0f, d01[1], c2S[c + 1]);
        float e2 = fmaf(-2.0f, d23[0], c2S[c + 2]);
        float e3 = fmaf(-2.0f, d23[1], c2S[c + 3]);
        float e4 = fmaf(-2.0f, d45[0], c2S[c + 4]);
        float e5 = fmaf(-2.0f, d45[1], c2S[c + 5]);
        float e6 = fmaf(-2.0f, d67[0], c2S[c + 6]);
        float e7 = fmaf(-2.0f, d67[1], c2S[c + 7]);
        // value-only min of the 8 (order-free for the value; no NaN inputs)
        float m = fminf(fminf(fminf(e0, e1), fminf(e2, e3)),
                        fminf(fminf(e4, e5), fminf(e6, e7)));
        if (m < best) { best = m; cbase = c; }   // strict '<': first block wins
    }

    // ---- re-scan winning 8-block with the identical chain (bit-identical) ----
    {
        const f32x2* pp = cbq + (size_t)(cbase >> 1) * DSUB;
        f32x2 d01 = {0.f, 0.f}, d23 = {0.f, 0.f};
        f32x2 d45 = {0.f, 0.f}, d67 = {0.f, 0.f};
#pragma unroll
        for (int k = 0; k < 16; k++) {
            asm("v_pk_fma_f32 %0, %1, %2, %0" : "+v"(d01) : "v"(gg[k]), "s"(pp[k]));
            asm("v_pk_fma_f32 %0, %1, %2, %0" : "+v"(d23) : "v"(gg[k]), "s"(pp[DSUB + k]));
            asm("v_pk_fma_f32 %0, %1, %2, %0" : "+v"(d45) : "v"(gg[k]), "s"(pp[2 * DSUB + k]));
            asm("v_pk_fma_f32 %0, %1, %2, %0" : "+v"(d67) : "v"(gg[k]), "s"(pp[3 * DSUB + k]));
        }
        float ee[8];
        ee[0] = fmaf(-2.0f, d01[0], c2S[cbase + 0]);
        ee[1] = fmaf(-2.0f, d01[1], c2S[cbase + 1]);
        ee[2] = fmaf(-2.0f, d23[0], c2S[cbase + 2]);
        ee[3] = fmaf(-2.0f, d23[1], c2S[cbase + 3]);
        ee[4] = fmaf(-2.0f, d45[0], c2S[cbase + 4]);
        ee[5] = fmaf(-2.0f, d45[1], c2S[cbase + 5]);
        ee[6] = fmaf(-2.0f, d67[0], c2S[cbase + 6]);
        ee[7] = fmaf(-2.0f, d67[1], c2S[cbase + 7]);
        float bst = FLT_MAX; int bi = 0;
#pragma unroll
        for (int j = 0; j < 8; j++)
            if (ee[j] < bst) { bst = ee[j]; bi = j; }   // first-index-wins
        pbest[(size_t)sub * 4 + q] = bst;
        pidx[(size_t)sub * 4 + q]  = c0 + cbase + bi;
    }
}

// Merge the 4 quarter-results (in order -> first-index tie semantics),
// dequantize, cast to bf16. Uq stored [16384][64] row-major; Bq stored
// transposed as BqT [4096 cols][64 k] for MFMA B-fragment loads.
__global__ __launch_bounds__(256) void pq_combine(
    const float* __restrict__ cb,
    const float* __restrict__ rsU, const float* __restrict__ rsB,
    const float* __restrict__ pbest, const int* __restrict__ pidx,
    __hip_bfloat16* __restrict__ Uqh, __hip_bfloat16* __restrict__ BqTh)
{
    int sub = blockIdx.x * 256 + threadIdx.x;   // < 81920 exactly
    float4 b4 = ((const float4*)pbest)[sub];
    int4   i4 = ((const int4*)pidx)[sub];
    float best = b4.x; int bi = i4.x;
    if (b4.y < best) { best = b4.y; bi = i4.y; }
    if (b4.z < best) { best = b4.z; bi = i4.z; }
    if (b4.w < best) { best = b4.w; bi = i4.w; }

    const float* cp = cb + (size_t)bi * DSUB;
    if (sub < NSUB_U) {
        float rs = rsU[sub >> 2];
        union { __hip_bfloat16 h[16]; uint4 u4[2]; } u;
#pragma unroll
        for (int j = 0; j < 16; j++) u.h[j] = __float2bfloat16(cp[j] * rs);
        uint4* dst = (uint4*)(Uqh + (size_t)sub * DSUB);
        dst[0] = u.u4[0];
        dst[1] = u.u4[1];
    } else {
        int s = sub - NSUB_U;
        int kk = s >> 8;                 // B row (k index), 0..63
        int dbase = (s & 255) * DSUB;    // output column base
        float rs = rsB[kk];
#pragma unroll
        for (int j = 0; j < 16; j++)
            BqTh[(size_t)(dbase + j) * 64 + kk] = __float2bfloat16(cp[j] * rs);
    }
}

// C[16384,4096] = Uq @ Bq via mfma_f32_16x16x32_bf16, K=64 (2 mfma per tile).
// One wave computes a 16-row x 64-col strip (4 n-tiles). HBM-write-bound;
// nontemporal stores keep C from churning L2.
__global__ __launch_bounds__(256) void mm_mfma(
    const __hip_bfloat16* __restrict__ A,   // [16384][64]
    const __hip_bfloat16* __restrict__ BT,  // [4096][64]
    float* __restrict__ C)
{
    int wave = threadIdx.x >> 6;
    int lane = threadIdx.x & 63;
    int rb  = ((blockIdx.y << 2) | wave) << 4;   // row base, 16 rows
    int cb0 = blockIdx.x << 6;                   // col base, 64 cols
    int mrow = lane & 15;
    int quad = lane >> 4;
    int kidx = quad * 8;

    const s16x8* ap = (const s16x8*)(A + (size_t)(rb + mrow) * 64 + kidx);
    s16x8 a0 = ap[0];     // k in [kidx, kidx+8)
    s16x8 a1 = ap[4];     // k in [32+kidx, 32+kidx+8)

    f32x4 acc[4] = {};
#pragma unroll
    for (int nt = 0; nt < 4; nt++) {
        const s16x8* bp =
            (const s16x8*)(BT + (size_t)(cb0 + nt * 16 + mrow) * 64 + kidx);
        s16x8 b0 = bp[0];
        s16x8 b1 = bp[4];
        acc[nt] = __builtin_amdgcn_mfma_f32_16x16x32_bf16(a0, b0, acc[nt], 0, 0, 0);
        acc[nt] = __builtin_amdgcn_mfma_f32_16x16x32_bf16(a1, b1, acc[nt], 0, 0, 0);
    }

#pragma unroll
    for (int nt = 0; nt < 4; nt++) {
#pragma unroll
        for (int i = 0; i < 4; i++) {
            __builtin_nontemporal_store(
                acc[nt][i],
                &C[(size_t)(rb + quad * 4 + i) * 4096 + (cb0 + nt * 16 + mrow)]);
        }
    }
}

extern "C" void kernel_launch(void* const* d_in, const int* in_sizes, int n_in,
                              void* d_out, int out_size, void* d_ws, size_t ws_size,
                              hipStream_t stream) {
    const float* U    = (const float*)d_in[0];   // [16384,64]
    const float* B    = (const float*)d_in[1];   // [64,4096]
    const float* rsU  = (const float*)d_in[2];   // [16384,1]
    const float* rsB  = (const float*)d_in[3];   // [64,1]
    const float* cb   = (const float*)d_in[4];   // [2048,16]
    float* C = (float*)d_out;                    // [16384,4096]

    char* w = (char*)d_ws;                       // needs ~5.25 MB
    float* pbest = (float*)(w + OFF_PBEST);
    int*   pidx  = (int*)(w + OFF_PIDX);
    f32x2* cbpk  = (f32x2*)(w + OFF_CBPK);
    __hip_bfloat16* Uqh  = (__hip_bfloat16*)(w + OFF_UQH);
    __hip_bfloat16* BqTh = (__hip_bfloat16*)(w + OFF_BQTH);

    pq_prepack<<<64, 256, 0, stream>>>(cb, cbpk);
    pq_partial<<<(NSUB / 256) * NQ, 256, 0, stream>>>(U, B, rsU, rsB, cb, cbpk,
                                                      pbest, pidx);
    pq_combine<<<NSUB / 256, 256, 0, stream>>>(cb, rsU, rsB, pbest, pidx,
                                               Uqh, BqTh);
    mm_mfma<<<dim3(64, 256), 256, 0, stream>>>(Uqh, BqTh, C);
}